// Round 12
// baseline (59.108 us; speedup 1.0000x reference)
//
#include <hip/hip_runtime.h>

#define OUTN 400
#define THRESH 0.7f
#define BB 32
#define HH 512
#define WW 512
#define CC 3
#define BIGI 0x7FFFFFFF

#define CHUNKS_PB 32                    // bounds chunks per batch
#define ROWS_PC   (HH / CHUNKS_PB)      // 16 rows per chunk
#define PXPB      (OUTN * OUTN)         // 160000 px per batch
#define TPB       320                   // resize threads per block (5 waves)
#define ROWS_PBLK 4                     // output rows per resize block
#define BANDS_PB  (OUTN / ROWS_PBLK)    // 100 bands per batch
#define RGRID     (BB * BANDS_PB)       // 3200 blocks, divisible by 8
#define NXCD      8
#define SROWS     6                     // staged source rows (1.2775*3+1 < 6)
#define ROWF      (WW * CC)             // 1536 floats per source row

typedef float vfloat4 __attribute__((ext_vector_type(4)));

// Per-(batch,chunk) partial bounds. Nontemporal loads: tensor is read-once.
__global__ void __launch_bounds__(256) bounds_part_kernel(
        const float* __restrict__ tensor,
        int4* __restrict__ part) {
    const int task  = blockIdx.x;            // 0..1023
    const int b     = task >> 5;
    const int chunk = task & 31;

    const vfloat4* base = (const vfloat4*)(tensor + (size_t)b * HH * WW
                                                  + (size_t)chunk * ROWS_PC * WW);

    int minR = BIGI, maxR = -1, minC = BIGI, maxC = -1;

    #pragma unroll
    for (int it = 0; it < 8; ++it) {
        int p = threadIdx.x + it * 256;
        vfloat4 v = __builtin_nontemporal_load(base + p);
        int row  = p >> 7;
        int col0 = (p & 127) * 4;
        int mask = (v.x > THRESH ? 1 : 0) | (v.y > THRESH ? 2 : 0)
                 | (v.z > THRESH ? 4 : 0) | (v.w > THRESH ? 8 : 0);
        if (mask) {
            minR = min(minR, row);
            maxR = max(maxR, row);
            minC = min(minC, col0 + __builtin_ctz(mask));
            maxC = max(maxC, col0 + (31 - __builtin_clz(mask)));
        }
    }

    #pragma unroll
    for (int off = 32; off > 0; off >>= 1) {
        minR = min(minR, __shfl_down(minR, off));
        maxR = max(maxR, __shfl_down(maxR, off));
        minC = min(minC, __shfl_down(minC, off));
        maxC = max(maxC, __shfl_down(maxC, off));
    }

    __shared__ int s[4];
    if (threadIdx.x == 0) { s[0] = BIGI; s[1] = -1; s[2] = BIGI; s[3] = -1; }
    __syncthreads();
    if ((threadIdx.x & 63) == 0) {
        atomicMin(&s[0], minR); atomicMax(&s[1], maxR);
        atomicMin(&s[2], minC); atomicMax(&s[3], maxC);
    }
    __syncthreads();
    if (threadIdx.x == 0) {
        int4 r;
        if (s[1] >= 0) {
            r.x = s[0] + chunk * ROWS_PC;
            r.y = s[1] + chunk * ROWS_PC;
            r.z = s[2];
            r.w = s[3];
        } else {
            r.x = BIGI; r.y = -1; r.z = BIGI; r.w = -1;
        }
        part[task] = r;
    }
}

__device__ inline int4 fold_bounds(const int4* __restrict__ part, int b, int lane) {
    int4 p = part[b * CHUNKS_PB + (lane & 31)];
    #pragma unroll
    for (int off = 1; off < 32; off <<= 1) {
        p.x = min(p.x, __shfl_xor(p.x, off));
        p.y = max(p.y, __shfl_xor(p.y, off));
        p.z = min(p.z, __shfl_xor(p.z, off));
        p.w = max(p.w, __shfl_xor(p.w, off));
    }
    if (p.y < 0) { p.x = 0; p.y = HH - 1; }   // all-false mask => [0, n-1]
    if (p.w < 0) { p.z = 0; p.w = WW - 1; }
    return p;
}

// Band-staged resize: block = 4 output rows (1600 px). The <=6 source rows
// feeding them are staged in LDS via coalesced float4 loads (36 KB, 4 blk/CU);
// texel reads then hit LDS, global reads are a pure stream.
__global__ void __launch_bounds__(TPB) resize_kernel(
        const float* __restrict__ img,
        const int4* __restrict__ part,
        float* __restrict__ out) {
    // bijective XCD swizzle (RGRID = 3200 divisible by 8)
    const int logical = (blockIdx.x % NXCD) * (RGRID / NXCD) + blockIdx.x / NXCD;
    const int t     = threadIdx.x;
    const int b     = logical / BANDS_PB;            // block-uniform batch
    const int orow0 = (logical % BANDS_PB) * ROWS_PBLK;

    int4 f = fold_bounds(part, b, t & 63);
    const int minR = f.x, maxR = f.y, minC = f.z, maxC = f.w;

    // source-row window for this band (uniform across block)
    const float sizeR  = (float)(maxR - minR);
    const float hiClpR = fmaxf(sizeR - 1.0f, 0.0f);
    const int   imaxR  = max(maxR - minR - 1, 0);

    float s0 = ((float)orow0 + 0.5f) * sizeR / (float)OUTN - 0.5f;
    s0 = fminf(fmaxf(s0, 0.0f), hiClpR);
    int rstart = minR + (int)floorf(s0);
    rstart = min(rstart, HH - SROWS);                // keep window inside image

    __shared__ float lds[SROWS * ROWF];              // 36 KB

    // stage: SROWS full source rows, coalesced float4
    {
        const vfloat4* src = (const vfloat4*)(img + (size_t)b * (HH * ROWF)
                                                  + (size_t)rstart * ROWF);
        vfloat4* dst = (vfloat4*)lds;
        for (int p = t; p < SROWS * (ROWF / 4); p += TPB)
            dst[p] = src[p];
    }
    __syncthreads();

    // compute: 80 threads per output row, 5 consecutive px per thread
    const int row   = orow0 + t / 80;                // output row
    const int ocol0 = (t % 80) * 5;

    // row coords (matches _axis_coords exactly)
    float srcR = ((float)row + 0.5f) * sizeR / (float)OUTN - 0.5f;
    srcR = fminf(fmaxf(srcR, 0.0f), hiClpR);
    int   i0 = (int)floorf(srcR);
    int   i1 = min(i0 + 1, imaxR);
    float wr = srcR - (float)i0;
    const float* __restrict__ row0 = lds + (size_t)(minR + i0 - rstart) * ROWF;
    const float* __restrict__ row1 = lds + (size_t)(minR + i1 - rstart) * ROWF;
    const float omr = 1.0f - wr;

    const float sizeC  = (float)(maxC - minC);
    const float hiClpC = fmaxf(sizeC - 1.0f, 0.0f);
    const int   jmaxC  = max(maxC - minC - 1, 0);

    float res[15];
    #pragma unroll
    for (int k = 0; k < 5; ++k) {
        float srcC = ((float)(ocol0 + k) + 0.5f) * sizeC / (float)OUTN - 0.5f;
        srcC = fminf(fmaxf(srcC, 0.0f), hiClpC);
        int   j0 = (int)floorf(srcC);
        int   j1 = min(j0 + 1, jmaxC);
        float wc = srcC - (float)j0;
        int c0 = (minC + j0) * CC, c1 = (minC + j1) * CC;
        float omc = 1.0f - wc;
        #pragma unroll
        for (int ch = 0; ch < CC; ++ch) {
            float top = row0[c0 + ch] * omc + row0[c1 + ch] * wc;
            float bot = row1[c0 + ch] * omc + row1[c1 + ch] * wc;
            res[k * 3 + ch] = top * omr + bot * wr;
        }
    }

    // store: 60 contiguous bytes per thread (wave covers 3840 B contiguous)
    float* o = out + ((size_t)b * PXPB + (size_t)row * OUTN + ocol0) * CC;
    #pragma unroll
    for (int i = 0; i < 15; ++i)
        __builtin_nontemporal_store(res[i], o + i);
}

extern "C" void kernel_launch(void* const* d_in, const int* in_sizes, int n_in,
                              void* d_out, int out_size, void* d_ws, size_t ws_size,
                              hipStream_t stream) {
    const float* image  = (const float*)d_in[0];
    const float* tensor = (const float*)d_in[1];
    float* out  = (float*)d_out;
    int4*  part = (int4*)d_ws;   // 1024 * 16 B = 16 KB

    hipLaunchKernelGGL(bounds_part_kernel, dim3(BB * CHUNKS_PB), dim3(256), 0, stream,
                       tensor, part);

    hipLaunchKernelGGL(resize_kernel, dim3(RGRID), dim3(TPB), 0, stream,
                       image, part, out);
}

// Round 13
// 38.550 us; speedup vs baseline: 1.5333x; 1.5333x over previous
//
#include <hip/hip_runtime.h>

#define OUTN 400
#define THRESH 0.7f
#define BB 32
#define HH 512
#define WW 512
#define CC 3
#define BIGI 0x7FFFFFFF

#define CHUNKS_PB 32                    // bounds chunks per batch
#define ROWS_PC   (HH / CHUNKS_PB)      // 16 rows per chunk
#define PXPB      (OUTN * OUTN)         // 160000 px per batch
#define TPB       320                   // resize threads per block (5 waves)
#define PXB       (TPB * 2)             // 640 px per block -> 250 blocks/batch exact
#define BLKS_PB   (PXPB / PXB)          // 250
#define NXCD      8
#define RGRID     (BB * BLKS_PB)        // 8000 resize blocks, divisible by 8

typedef float vfloat4 __attribute__((ext_vector_type(4)));

// ---------------------------------------------------------------------------
// Border pre-check: for uniform-random data the bbox is (almost surely) the
// full frame. Scan the 4 border lines per batch (~0.5 MB total vs 33.5 MB);
// if row0/row511/col0/col511 each contain any element > THRESH, the full scan
// would provably return {0,511,0,511} -> publish it and set flag[b] so the
// full scan early-exits. Any other input falls back to the full scan.
// ---------------------------------------------------------------------------
__global__ void __launch_bounds__(256) border_kernel(
        const float* __restrict__ tensor,
        int4* __restrict__ part,
        int* __restrict__ flag) {
    const int b = blockIdx.x;
    const int t = threadIdx.x;
    const float* tb = tensor + (size_t)b * (HH * WW);

    bool r0any = false, r1any = false, c0any = false, c1any = false;

    // rows: threads 0..127 scan row 0 (128 float4), 128..255 scan row 511
    if (t < 128) {
        vfloat4 v = ((const vfloat4*)tb)[t];
        r0any = (v.x > THRESH) | (v.y > THRESH) | (v.z > THRESH) | (v.w > THRESH);
    } else {
        vfloat4 v = ((const vfloat4*)(tb + (size_t)(HH - 1) * WW))[t - 128];
        r1any = (v.x > THRESH) | (v.y > THRESH) | (v.z > THRESH) | (v.w > THRESH);
    }
    // cols: each thread checks 2 rows of col 0 and col 511 (strided loads)
    {
        float a0 = tb[(size_t)t * WW];
        float a1 = tb[(size_t)(t + 256) * WW];
        c0any = (a0 > THRESH) | (a1 > THRESH);
        float b0 = tb[(size_t)t * WW + (WW - 1)];
        float b1 = tb[(size_t)(t + 256) * WW + (WW - 1)];
        c1any = (b0 > THRESH) | (b1 > THRESH);
    }

    __shared__ int s[4];
    if (t == 0) { s[0] = 0; s[1] = 0; s[2] = 0; s[3] = 0; }
    __syncthreads();
    bool a0 = __any(r0any), a1 = __any(r1any), a2 = __any(c0any), a3 = __any(c1any);
    if ((t & 63) == 0) {
        if (a0) atomicOr(&s[0], 1);
        if (a1) atomicOr(&s[1], 1);
        if (a2) atomicOr(&s[2], 1);
        if (a3) atomicOr(&s[3], 1);
    }
    __syncthreads();

    const bool full = s[0] && s[1] && s[2] && s[3];
    if (t == 0) flag[b] = full ? 1 : 0;
    if (full && t < CHUNKS_PB) {
        int4 fb; fb.x = 0; fb.y = HH - 1; fb.z = 0; fb.w = WW - 1;
        part[b * CHUNKS_PB + t] = fb;
    }
}

// Per-(batch,chunk) partial bounds (full scan). Early-exits when the border
// pre-check already proved full-frame bounds. Nontemporal loads: read-once.
__global__ void __launch_bounds__(256) bounds_part_kernel(
        const float* __restrict__ tensor,
        const int* __restrict__ flag,
        int4* __restrict__ part) {
    const int task  = blockIdx.x;            // 0..1023
    const int b     = task >> 5;
    const int chunk = task & 31;

    if (flag[b]) return;                     // border pre-check settled it

    const vfloat4* base = (const vfloat4*)(tensor + (size_t)b * HH * WW
                                                  + (size_t)chunk * ROWS_PC * WW);

    int minR = BIGI, maxR = -1, minC = BIGI, maxC = -1;

    #pragma unroll
    for (int it = 0; it < 8; ++it) {
        int p = threadIdx.x + it * 256;
        vfloat4 v = __builtin_nontemporal_load(base + p);
        int row  = p >> 7;
        int col0 = (p & 127) * 4;
        int mask = (v.x > THRESH ? 1 : 0) | (v.y > THRESH ? 2 : 0)
                 | (v.z > THRESH ? 4 : 0) | (v.w > THRESH ? 8 : 0);
        if (mask) {
            minR = min(minR, row);
            maxR = max(maxR, row);
            minC = min(minC, col0 + __builtin_ctz(mask));
            maxC = max(maxC, col0 + (31 - __builtin_clz(mask)));
        }
    }

    #pragma unroll
    for (int off = 32; off > 0; off >>= 1) {
        minR = min(minR, __shfl_down(minR, off));
        maxR = max(maxR, __shfl_down(maxR, off));
        minC = min(minC, __shfl_down(minC, off));
        maxC = max(maxC, __shfl_down(maxC, off));
    }

    __shared__ int s[4];
    if (threadIdx.x == 0) { s[0] = BIGI; s[1] = -1; s[2] = BIGI; s[3] = -1; }
    __syncthreads();
    if ((threadIdx.x & 63) == 0) {
        atomicMin(&s[0], minR); atomicMax(&s[1], maxR);
        atomicMin(&s[2], minC); atomicMax(&s[3], maxC);
    }
    __syncthreads();
    if (threadIdx.x == 0) {
        int4 r;
        if (s[1] >= 0) {
            r.x = s[0] + chunk * ROWS_PC;
            r.y = s[1] + chunk * ROWS_PC;
            r.z = s[2];
            r.w = s[3];
        } else {
            r.x = BIGI; r.y = -1; r.z = BIGI; r.w = -1;
        }
        part[task] = r;
    }
}

__device__ inline int4 fold_bounds(const int4* __restrict__ part, int b, int lane) {
    int4 p = part[b * CHUNKS_PB + (lane & 31)];
    #pragma unroll
    for (int off = 1; off < 32; off <<= 1) {
        p.x = min(p.x, __shfl_xor(p.x, off));
        p.y = max(p.y, __shfl_xor(p.y, off));
        p.z = min(p.z, __shfl_xor(p.z, off));
        p.w = max(p.w, __shfl_xor(p.w, off));
    }
    if (p.y < 0) { p.x = 0; p.y = HH - 1; }   // all-false mask => [0, n-1]
    if (p.w < 0) { p.z = 0; p.w = WW - 1; }
    return p;
}

__device__ inline void ld3(const float* __restrict__ p, float* d) {
    d[0] = p[0]; d[1] = p[1]; d[2] = p[2];
}

// Round-10 resize (best measured): 2 consecutive px per thread, XCD-swizzled
// batch affinity (each XCD's 4 batches' 3.1 MB slices stream through its L2),
// SGPR image base, 8 batched dwordx3 gathers, scalar NT stores.
__global__ void __launch_bounds__(TPB) resize_kernel(
        const float* __restrict__ img,
        const int4* __restrict__ part,
        float* __restrict__ out) {
    const int logical = (blockIdx.x % NXCD) * (RGRID / NXCD) + blockIdx.x / NXCD;

    const int t    = threadIdx.x;
    const int b    = logical / BLKS_PB;                    // block-uniform
    const int rem  = (logical % BLKS_PB) * PXB + t * 2;    // px within batch
    const int lane = t & 63;

    int4 f = fold_bounds(part, b, lane);
    const int minR = f.x, maxR = f.y, minC = f.z, maxC = f.w;

    const int ocol = rem % OUTN;     // even; pair = {ocol, ocol+1} same row
    const int orow = rem / OUTN;

    float sizeR = (float)(maxR - minR);
    float srcR  = ((float)orow + 0.5f) * sizeR * (1.0f / OUTN) - 0.5f;
    srcR = fminf(fmaxf(srcR, 0.0f), fmaxf(sizeR - 1.0f, 0.0f));
    int   i0 = (int)floorf(srcR);
    int   i1 = min(i0 + 1, max(maxR - minR - 1, 0));
    float wr = srcR - (float)i0;
    const int ro0 = (minR + i0) * (WW * CC);
    const int ro1 = (minR + i1) * (WW * CC);

    const float sizeC  = (float)(maxC - minC);
    const float hiClip = fmaxf(sizeC - 1.0f, 0.0f);
    const int   jmax   = max(maxC - minC - 1, 0);

    float srcC0 = ((float)ocol + 0.5f) * sizeC * (1.0f / OUTN) - 0.5f;
    srcC0 = fminf(fmaxf(srcC0, 0.0f), hiClip);
    int   j00 = (int)floorf(srcC0);
    int   j01 = min(j00 + 1, jmax);
    float wc0 = srcC0 - (float)j00;
    const int c00 = (minC + j00) * CC, c01 = (minC + j01) * CC;

    float srcC1 = ((float)ocol + 1.5f) * sizeC * (1.0f / OUTN) - 0.5f;
    srcC1 = fminf(fmaxf(srcC1, 0.0f), hiClip);
    int   j10 = (int)floorf(srcC1);
    int   j11 = min(j10 + 1, jmax);
    float wc1 = srcC1 - (float)j10;
    const int c10 = (minC + j10) * CC, c11 = (minC + j11) * CC;

    const float* __restrict__ ib = img + (size_t)b * (HH * WW * CC);  // SGPR base

    float a00[3], a01[3], a10[3], a11[3];   // pixel 0
    float d00[3], d01[3], d10[3], d11[3];   // pixel 1
    ld3(ib + ro0 + c00, a00);
    ld3(ib + ro0 + c01, a01);
    ld3(ib + ro1 + c00, a10);
    ld3(ib + ro1 + c01, a11);
    ld3(ib + ro0 + c10, d00);
    ld3(ib + ro0 + c11, d01);
    ld3(ib + ro1 + c10, d10);
    ld3(ib + ro1 + c11, d11);

    float res[6];
    {
        float omc = 1.0f - wc0, omr = 1.0f - wr;
        #pragma unroll
        for (int ch = 0; ch < CC; ++ch) {
            float top = a00[ch] * omc + a01[ch] * wc0;
            float bot = a10[ch] * omc + a11[ch] * wc0;
            res[ch] = top * omr + bot * wr;
        }
        omc = 1.0f - wc1;
        #pragma unroll
        for (int ch = 0; ch < CC; ++ch) {
            float top = d00[ch] * omc + d01[ch] * wc1;
            float bot = d10[ch] * omc + d11[ch] * wc1;
            res[3 + ch] = top * omr + bot * wr;
        }
    }

    float* o = out + ((size_t)b * PXPB + (size_t)rem) * CC;
    #pragma unroll
    for (int i = 0; i < 6; ++i)
        __builtin_nontemporal_store(res[i], o + i);
}

extern "C" void kernel_launch(void* const* d_in, const int* in_sizes, int n_in,
                              void* d_out, int out_size, void* d_ws, size_t ws_size,
                              hipStream_t stream) {
    const float* image  = (const float*)d_in[0];
    const float* tensor = (const float*)d_in[1];
    float* out  = (float*)d_out;
    int4*  part = (int4*)d_ws;                       // 1024 * 16 B
    int*   flag = (int*)(part + BB * CHUNKS_PB);     // 32 ints

    hipLaunchKernelGGL(border_kernel, dim3(BB), dim3(256), 0, stream,
                       tensor, part, flag);

    hipLaunchKernelGGL(bounds_part_kernel, dim3(BB * CHUNKS_PB), dim3(256), 0, stream,
                       tensor, flag, part);

    hipLaunchKernelGGL(resize_kernel, dim3(RGRID), dim3(TPB), 0, stream,
                       image, part, out);
}

// Round 14
// 34.692 us; speedup vs baseline: 1.7038x; 1.1112x over previous
//
#include <hip/hip_runtime.h>

#define OUTN 400
#define THRESH 0.7f
#define BB 32
#define HH 512
#define WW 512
#define CC 3
#define BIGI 0x7FFFFFFF

#define PXPB      (OUTN * OUTN)         // 160000 px per batch
#define TPB       320                   // resize threads per block (5 waves)
#define PXB       (TPB * 2)             // 640 px per block -> 250 blocks/batch exact
#define BLKS_PB   (PXPB / PXB)          // 250
#define NXCD      8
#define RGRID     (BB * BLKS_PB)        // 8000 resize blocks, divisible by 8

typedef float vfloat4 __attribute__((ext_vector_type(4)));

// ---------------------------------------------------------------------------
// One block per batch: border pre-check, then (only if inconclusive) a full
// in-block scan. Writes FINAL bounds directly -> resize needs no fold.
// Fast path: if row0 / row511 / col0 / col511 each contain any element
// > THRESH, the bbox is provably {0,511,0,511}.
// ---------------------------------------------------------------------------
__global__ void __launch_bounds__(256) bounds_final_kernel(
        const float* __restrict__ tensor,
        int4* __restrict__ finals) {
    const int b = blockIdx.x;
    const int t = threadIdx.x;
    const float* tb = tensor + (size_t)b * (HH * WW);

    bool r0any = false, r1any = false, c0any = false, c1any = false;

    // rows: threads 0..127 scan row 0 (128 float4), 128..255 scan row 511
    if (t < 128) {
        vfloat4 v = ((const vfloat4*)tb)[t];
        r0any = (v.x > THRESH) | (v.y > THRESH) | (v.z > THRESH) | (v.w > THRESH);
    } else {
        vfloat4 v = ((const vfloat4*)(tb + (size_t)(HH - 1) * WW))[t - 128];
        r1any = (v.x > THRESH) | (v.y > THRESH) | (v.z > THRESH) | (v.w > THRESH);
    }
    // cols: each thread checks 2 rows of col 0 and col 511
    {
        float a0 = tb[(size_t)t * WW];
        float a1 = tb[(size_t)(t + 256) * WW];
        c0any = (a0 > THRESH) | (a1 > THRESH);
        float b0 = tb[(size_t)t * WW + (WW - 1)];
        float b1 = tb[(size_t)(t + 256) * WW + (WW - 1)];
        c1any = (b0 > THRESH) | (b1 > THRESH);
    }

    __shared__ int s[4];
    if (t == 0) { s[0] = 0; s[1] = 0; s[2] = 0; s[3] = 0; }
    __syncthreads();
    bool a0 = __any(r0any), a1 = __any(r1any), a2 = __any(c0any), a3 = __any(c1any);
    if ((t & 63) == 0) {
        if (a0) atomicOr(&s[0], 1);
        if (a1) atomicOr(&s[1], 1);
        if (a2) atomicOr(&s[2], 1);
        if (a3) atomicOr(&s[3], 1);
    }
    __syncthreads();

    if (s[0] && s[1] && s[2] && s[3]) {
        if (t == 0) {
            int4 f; f.x = 0; f.y = HH - 1; f.z = 0; f.w = WW - 1;
            finals[b] = f;
        }
        return;
    }

    // ---- fallback: full scan of this batch within the block (rare path) ----
    int minR = BIGI, maxR = -1, minC = BIGI, maxC = -1;
    const vfloat4* base = (const vfloat4*)tb;
    for (int p = t; p < (HH * WW) / 4; p += 256) {
        vfloat4 v = __builtin_nontemporal_load(base + p);
        int row  = p >> 7;                // 128 float4 per row
        int col0 = (p & 127) * 4;
        int mask = (v.x > THRESH ? 1 : 0) | (v.y > THRESH ? 2 : 0)
                 | (v.z > THRESH ? 4 : 0) | (v.w > THRESH ? 8 : 0);
        if (mask) {
            minR = min(minR, row);
            maxR = max(maxR, row);
            minC = min(minC, col0 + __builtin_ctz(mask));
            maxC = max(maxC, col0 + (31 - __builtin_clz(mask)));
        }
    }

    #pragma unroll
    for (int off = 32; off > 0; off >>= 1) {
        minR = min(minR, __shfl_down(minR, off));
        maxR = max(maxR, __shfl_down(maxR, off));
        minC = min(minC, __shfl_down(minC, off));
        maxC = max(maxC, __shfl_down(maxC, off));
    }

    __shared__ int r[4];
    if (t == 0) { r[0] = BIGI; r[1] = -1; r[2] = BIGI; r[3] = -1; }
    __syncthreads();
    if ((t & 63) == 0) {
        atomicMin(&r[0], minR); atomicMax(&r[1], maxR);
        atomicMin(&r[2], minC); atomicMax(&r[3], maxC);
    }
    __syncthreads();
    if (t == 0) {
        int4 f;
        if (r[1] >= 0) { f.x = r[0]; f.y = r[1]; } else { f.x = 0; f.y = HH - 1; }
        if (r[3] >= 0) { f.z = r[2]; f.w = r[3]; } else { f.z = 0; f.w = WW - 1; }
        finals[b] = f;   // all-false axis => [0, n-1] (argmax semantics)
    }
}

__device__ inline void ld3(const float* __restrict__ p, float* d) {
    d[0] = p[0]; d[1] = p[1]; d[2] = p[2];
}

// Round-10/13 resize (best measured): 2 consecutive px per thread, XCD batch
// affinity, SGPR image base, 8 batched dwordx3 gathers, scalar NT stores.
// Bounds now come from finals[b] via a block-uniform (scalar) load.
__global__ void __launch_bounds__(TPB) resize_kernel(
        const float* __restrict__ img,
        const int4* __restrict__ finals,
        float* __restrict__ out) {
    const int logical = (blockIdx.x % NXCD) * (RGRID / NXCD) + blockIdx.x / NXCD;

    const int t    = threadIdx.x;
    const int b    = logical / BLKS_PB;                    // block-uniform
    const int rem  = (logical % BLKS_PB) * PXB + t * 2;    // px within batch

    const int4 f = finals[b];                              // scalar load
    const int minR = f.x, maxR = f.y, minC = f.z, maxC = f.w;

    const int ocol = rem % OUTN;     // even; pair = {ocol, ocol+1} same row
    const int orow = rem / OUTN;

    float sizeR = (float)(maxR - minR);
    float srcR  = ((float)orow + 0.5f) * sizeR * (1.0f / OUTN) - 0.5f;
    srcR = fminf(fmaxf(srcR, 0.0f), fmaxf(sizeR - 1.0f, 0.0f));
    int   i0 = (int)floorf(srcR);
    int   i1 = min(i0 + 1, max(maxR - minR - 1, 0));
    float wr = srcR - (float)i0;
    const int ro0 = (minR + i0) * (WW * CC);
    const int ro1 = (minR + i1) * (WW * CC);

    const float sizeC  = (float)(maxC - minC);
    const float hiClip = fmaxf(sizeC - 1.0f, 0.0f);
    const int   jmax   = max(maxC - minC - 1, 0);

    float srcC0 = ((float)ocol + 0.5f) * sizeC * (1.0f / OUTN) - 0.5f;
    srcC0 = fminf(fmaxf(srcC0, 0.0f), hiClip);
    int   j00 = (int)floorf(srcC0);
    int   j01 = min(j00 + 1, jmax);
    float wc0 = srcC0 - (float)j00;
    const int c00 = (minC + j00) * CC, c01 = (minC + j01) * CC;

    float srcC1 = ((float)ocol + 1.5f) * sizeC * (1.0f / OUTN) - 0.5f;
    srcC1 = fminf(fmaxf(srcC1, 0.0f), hiClip);
    int   j10 = (int)floorf(srcC1);
    int   j11 = min(j10 + 1, jmax);
    float wc1 = srcC1 - (float)j10;
    const int c10 = (minC + j10) * CC, c11 = (minC + j11) * CC;

    const float* __restrict__ ib = img + (size_t)b * (HH * WW * CC);  // SGPR base

    float a00[3], a01[3], a10[3], a11[3];   // pixel 0
    float d00[3], d01[3], d10[3], d11[3];   // pixel 1
    ld3(ib + ro0 + c00, a00);
    ld3(ib + ro0 + c01, a01);
    ld3(ib + ro1 + c00, a10);
    ld3(ib + ro1 + c01, a11);
    ld3(ib + ro0 + c10, d00);
    ld3(ib + ro0 + c11, d01);
    ld3(ib + ro1 + c10, d10);
    ld3(ib + ro1 + c11, d11);

    float res[6];
    {
        float omc = 1.0f - wc0, omr = 1.0f - wr;
        #pragma unroll
        for (int ch = 0; ch < CC; ++ch) {
            float top = a00[ch] * omc + a01[ch] * wc0;
            float bot = a10[ch] * omc + a11[ch] * wc0;
            res[ch] = top * omr + bot * wr;
        }
        omc = 1.0f - wc1;
        #pragma unroll
        for (int ch = 0; ch < CC; ++ch) {
            float top = d00[ch] * omc + d01[ch] * wc1;
            float bot = d10[ch] * omc + d11[ch] * wc1;
            res[3 + ch] = top * omr + bot * wr;
        }
    }

    float* o = out + ((size_t)b * PXPB + (size_t)rem) * CC;
    #pragma unroll
    for (int i = 0; i < 6; ++i)
        __builtin_nontemporal_store(res[i], o + i);
}

extern "C" void kernel_launch(void* const* d_in, const int* in_sizes, int n_in,
                              void* d_out, int out_size, void* d_ws, size_t ws_size,
                              hipStream_t stream) {
    const float* image  = (const float*)d_in[0];
    const float* tensor = (const float*)d_in[1];
    float* out    = (float*)d_out;
    int4*  finals = (int4*)d_ws;    // 32 * 16 B

    hipLaunchKernelGGL(bounds_final_kernel, dim3(BB), dim3(256), 0, stream,
                       tensor, finals);

    hipLaunchKernelGGL(resize_kernel, dim3(RGRID), dim3(TPB), 0, stream,
                       image, finals, out);
}

// Round 15
// 32.772 us; speedup vs baseline: 1.8036x; 1.0586x over previous
//
#include <hip/hip_runtime.h>

#define OUTN 400
#define THRESH 0.7f
#define BB 32
#define HH 512
#define WW 512
#define CC 3
#define BIGI 0x7FFFFFFF

#define PXPB      (OUTN * OUTN)         // 160000 px per batch
#define TPB       256                   // resize threads per block (4 waves)
#define PXB       TPB                   // 1 px per thread -> 625 blocks/batch exact
#define BLKS_PB   (PXPB / PXB)          // 625
#define NXCD      8
#define RGRID     (BB * BLKS_PB)        // 20000 resize blocks, divisible by 8

typedef float vfloat4 __attribute__((ext_vector_type(4)));

// ---------------------------------------------------------------------------
// One block per batch: border pre-check, then (only if inconclusive) a full
// in-block scan. Writes FINAL bounds directly.
// ---------------------------------------------------------------------------
__global__ void __launch_bounds__(256) bounds_final_kernel(
        const float* __restrict__ tensor,
        int4* __restrict__ finals) {
    const int b = blockIdx.x;
    const int t = threadIdx.x;
    const float* tb = tensor + (size_t)b * (HH * WW);

    bool r0any = false, r1any = false, c0any = false, c1any = false;

    if (t < 128) {
        vfloat4 v = ((const vfloat4*)tb)[t];
        r0any = (v.x > THRESH) | (v.y > THRESH) | (v.z > THRESH) | (v.w > THRESH);
    } else {
        vfloat4 v = ((const vfloat4*)(tb + (size_t)(HH - 1) * WW))[t - 128];
        r1any = (v.x > THRESH) | (v.y > THRESH) | (v.z > THRESH) | (v.w > THRESH);
    }
    {
        float a0 = tb[(size_t)t * WW];
        float a1 = tb[(size_t)(t + 256) * WW];
        c0any = (a0 > THRESH) | (a1 > THRESH);
        float b0 = tb[(size_t)t * WW + (WW - 1)];
        float b1 = tb[(size_t)(t + 256) * WW + (WW - 1)];
        c1any = (b0 > THRESH) | (b1 > THRESH);
    }

    __shared__ int s[4];
    if (t == 0) { s[0] = 0; s[1] = 0; s[2] = 0; s[3] = 0; }
    __syncthreads();
    bool a0 = __any(r0any), a1 = __any(r1any), a2 = __any(c0any), a3 = __any(c1any);
    if ((t & 63) == 0) {
        if (a0) atomicOr(&s[0], 1);
        if (a1) atomicOr(&s[1], 1);
        if (a2) atomicOr(&s[2], 1);
        if (a3) atomicOr(&s[3], 1);
    }
    __syncthreads();

    if (s[0] && s[1] && s[2] && s[3]) {
        if (t == 0) {
            int4 f; f.x = 0; f.y = HH - 1; f.z = 0; f.w = WW - 1;
            finals[b] = f;
        }
        return;
    }

    // ---- fallback: full scan of this batch within the block (rare path) ----
    int minR = BIGI, maxR = -1, minC = BIGI, maxC = -1;
    const vfloat4* base = (const vfloat4*)tb;
    for (int p = t; p < (HH * WW) / 4; p += 256) {
        vfloat4 v = __builtin_nontemporal_load(base + p);
        int row  = p >> 7;                // 128 float4 per row
        int col0 = (p & 127) * 4;
        int mask = (v.x > THRESH ? 1 : 0) | (v.y > THRESH ? 2 : 0)
                 | (v.z > THRESH ? 4 : 0) | (v.w > THRESH ? 8 : 0);
        if (mask) {
            minR = min(minR, row);
            maxR = max(maxR, row);
            minC = min(minC, col0 + __builtin_ctz(mask));
            maxC = max(maxC, col0 + (31 - __builtin_clz(mask)));
        }
    }

    #pragma unroll
    for (int off = 32; off > 0; off >>= 1) {
        minR = min(minR, __shfl_down(minR, off));
        maxR = max(maxR, __shfl_down(maxR, off));
        minC = min(minC, __shfl_down(minC, off));
        maxC = max(maxC, __shfl_down(maxC, off));
    }

    __shared__ int r[4];
    if (t == 0) { r[0] = BIGI; r[1] = -1; r[2] = BIGI; r[3] = -1; }
    __syncthreads();
    if ((t & 63) == 0) {
        atomicMin(&r[0], minR); atomicMax(&r[1], maxR);
        atomicMin(&r[2], minC); atomicMax(&r[3], maxC);
    }
    __syncthreads();
    if (t == 0) {
        int4 f;
        if (r[1] >= 0) { f.x = r[0]; f.y = r[1]; } else { f.x = 0; f.y = HH - 1; }
        if (r[3] >= 0) { f.z = r[2]; f.w = r[3]; } else { f.z = 0; f.w = WW - 1; }
        finals[b] = f;   // all-false axis => [0, n-1] (argmax semantics)
    }
}

__device__ inline void ld3(const float* __restrict__ p, float* d) {
    d[0] = p[0]; d[1] = p[1]; d[2] = p[2];
}

// 1 px per thread, 64 CONSECUTIVE px per wave: gather stride ~15.3 B/lane
// -> ~16 cachelines per gather instruction (vs ~31 at 2px/thread), store =
// 12 B/lane contiguous (12 lines/wave-instr). XCD batch affinity retained.
__global__ void __launch_bounds__(TPB) resize_kernel(
        const float* __restrict__ img,
        const int4* __restrict__ finals,
        float* __restrict__ out) {
    // bijective XCD swizzle (RGRID = 20000 divisible by 8)
    const int logical = (blockIdx.x % NXCD) * (RGRID / NXCD) + blockIdx.x / NXCD;

    const int t   = threadIdx.x;
    const int b   = logical / BLKS_PB;                   // block-uniform
    const int rem = (logical % BLKS_PB) * PXB + t;       // px within batch

    const int4 f = finals[b];                            // scalar load
    const int minR = f.x, maxR = f.y, minC = f.z, maxC = f.w;

    const int ocol = rem % OUTN;
    const int orow = rem / OUTN;

    float sizeR = (float)(maxR - minR);
    float srcR  = ((float)orow + 0.5f) * sizeR * (1.0f / OUTN) - 0.5f;
    srcR = fminf(fmaxf(srcR, 0.0f), fmaxf(sizeR - 1.0f, 0.0f));
    int   i0 = (int)floorf(srcR);
    int   i1 = min(i0 + 1, max(maxR - minR - 1, 0));
    float wr = srcR - (float)i0;
    const int ro0 = (minR + i0) * (WW * CC);
    const int ro1 = (minR + i1) * (WW * CC);

    float sizeC = (float)(maxC - minC);
    float srcC  = ((float)ocol + 0.5f) * sizeC * (1.0f / OUTN) - 0.5f;
    srcC = fminf(fmaxf(srcC, 0.0f), fmaxf(sizeC - 1.0f, 0.0f));
    int   j0 = (int)floorf(srcC);
    int   j1 = min(j0 + 1, max(maxC - minC - 1, 0));
    float wc = srcC - (float)j0;
    const int c0 = (minC + j0) * CC, c1 = (minC + j1) * CC;

    const float* __restrict__ ib = img + (size_t)b * (HH * WW * CC);  // SGPR base

    // load phase: 4 independent dwordx3 gathers issued together
    float a00[3], a01[3], a10[3], a11[3];
    ld3(ib + ro0 + c0, a00);
    ld3(ib + ro0 + c1, a01);
    ld3(ib + ro1 + c0, a10);
    ld3(ib + ro1 + c1, a11);

    // blend
    float res[3];
    {
        float omc = 1.0f - wc, omr = 1.0f - wr;
        #pragma unroll
        for (int ch = 0; ch < CC; ++ch) {
            float top = a00[ch] * omc + a01[ch] * wc;
            float bot = a10[ch] * omc + a11[ch] * wc;
            res[ch] = top * omr + bot * wr;
        }
    }

    // store: 12 contiguous bytes per lane; wave covers 768 B contiguous
    float* o = out + ((size_t)b * PXPB + (size_t)rem) * CC;
    __builtin_nontemporal_store(res[0], o + 0);
    __builtin_nontemporal_store(res[1], o + 1);
    __builtin_nontemporal_store(res[2], o + 2);
}

extern "C" void kernel_launch(void* const* d_in, const int* in_sizes, int n_in,
                              void* d_out, int out_size, void* d_ws, size_t ws_size,
                              hipStream_t stream) {
    const float* image  = (const float*)d_in[0];
    const float* tensor = (const float*)d_in[1];
    float* out    = (float*)d_out;
    int4*  finals = (int4*)d_ws;    // 32 * 16 B

    hipLaunchKernelGGL(bounds_final_kernel, dim3(BB), dim3(256), 0, stream,
                       tensor, finals);

    hipLaunchKernelGGL(resize_kernel, dim3(RGRID), dim3(TPB), 0, stream,
                       image, finals, out);
}